// Round 1
// baseline (839.571 us; speedup 1.0000x reference)
//
#include <hip/hip_runtime.h>
#include <math.h>

#define BN 4096

// ---- chunk tables: (base row in x, rows used) for the 31 masked means ----
// 0: q_sum (query_feat[:10])        rows 276..285
// 1..5:  s1  user_item_seq[-65:]    base 211+13t, 10 rows
// 6..10: s2  user_item_query[:50]   base 662+10t, 5 rows
// 11..15:s3  user_query_item[-50:]  base 612+10t, 5 rows
// 16..20:s4  user_query_seq[-65:]   base 397+13t, 10 rows
// 21..25:c1  query_item_query[-50:] base 512+10t, 5 rows
// 26..30:c2  query_user_item[-50:]  base 862+10t, 5 rows
__device__ const int c_base[31] = {
  276,
  211, 224, 237, 250, 263,
  662, 672, 682, 692, 702,
  612, 622, 632, 642, 652,
  397, 410, 423, 436, 449,
  512, 522, 532, 542, 552,
  862, 872, 882, 892, 902
};
__device__ const int c_rows[31] = {
  10,
  10,10,10,10,10,
  5,5,5,5,5,
  5,5,5,5,5,
  10,10,10,10,10,
  5,5,5,5,5,
  5,5,5,5,5
};

__device__ __forceinline__ float4 ld4(const float* p) { return *(const float4*)p; }
__device__ __forceinline__ float dot4(float4 a, float4 b) {
  return a.x*b.x + a.y*b.y + a.z*b.z + a.w*b.w;
}
__device__ __forceinline__ float sig_(float v) { return 1.0f / (1.0f + expf(-v)); }

// ---- Kernel A: global sign-counts -> L values (exact: integer sums < 2^24) ----
extern "C" __global__ __launch_bounds__(256)
void count_L_kernel(const float* __restrict__ x, float* __restrict__ Lout) {
  __shared__ float red[256];
  const int c = blockIdx.x;
  const int base = c_base[c];
  const int rows = c_rows[c];
  const int total = rows * BN;
  float s = 0.f;
  for (int i = threadIdx.x; i < total; i += 256) {
    float v = x[(size_t)(base + (i >> 12)) * BN + (i & 4095)];
    s += (v > 0.f ? 1.f : (v < 0.f ? -1.f : 0.f));
  }
  red[threadIdx.x] = s;
  __syncthreads();
  for (int off = 128; off > 0; off >>= 1) {
    if (threadIdx.x < off) red[threadIdx.x] += red[threadIdx.x + off];
    __syncthreads();
  }
  if (threadIdx.x == 0) {
    float n = red[0];
    float L = n > 1.f ? n : 1.f;
    Lout[c] = fminf(L, (float)rows);
  }
}

// masked-mean gather for 4 consecutive batch elems; lane = embed dim (coalesced)
__device__ __forceinline__ void gather4(const float* __restrict__ x,
                                        const float* __restrict__ we,
                                        float L, int base, int rows,
                                        int b0, int lane, float* m) {
  float a0 = 0.f, a1 = 0.f, a2 = 0.f, a3 = 0.f;
  for (int r = 0; r < rows; ++r) {
    if ((float)r < L) {           // uniform branch (L is global scalar)
      float4 iv = ld4(x + (size_t)(base + r) * BN + b0);
      a0 += we[(size_t)(int)iv.x * 64 + lane];
      a1 += we[(size_t)(int)iv.y * 64 + lane];
      a2 += we[(size_t)(int)iv.z * 64 + lane];
      a3 += we[(size_t)(int)iv.w * 64 + lane];
    }
  }
  m[0] = a0 / L; m[1] = a1 / L; m[2] = a2 / L; m[3] = a3 / L;
}

// ---- Kernel B: everything else. One wave = 4 batch elements, lane = dim. ----
extern "C" __global__ __launch_bounds__(256)
void model_kernel(
    const float* __restrict__ x,   const float* __restrict__ we,
    const float* __restrict__ Wih, const float* __restrict__ Whh,
    const float* __restrict__ bih, const float* __restrict__ bhh,
    const float* __restrict__ h0,  const float* __restrict__ c0,
    const float* __restrict__ wl,  const float* __restrict__ bl,
    const float* __restrict__ c1w, const float* __restrict__ c1b,
    const float* __restrict__ l1w, const float* __restrict__ l1b,
    const float* __restrict__ c2w, const float* __restrict__ c2b,
    const float* __restrict__ l2w, const float* __restrict__ l2b,
    const float* __restrict__ ww,  const float* __restrict__ wb,
    const float* __restrict__ cqw, const float* __restrict__ cqb,
    const float* __restrict__ cquw,const float* __restrict__ cqub,
    const float* __restrict__ dww, const float* __restrict__ dwb,
    const float* __restrict__ Lws, float* __restrict__ out)
{
  // per-wave scratch: cbuf = concat[448] per (wave,j); abuf = LSTM x|h (also
  // conv tmp + q|wide); sbuf = CNN steps (5x64)
  __shared__ __align__(16) float cbuf[4][4][448];
  __shared__ __align__(16) float abuf[4][4][128];
  __shared__ __align__(16) float sbuf[4][4][320];

  const int tid  = threadIdx.x;
  const int w    = tid >> 6;
  const int lane = tid & 63;
  const int b0   = blockIdx.x * 16 + w * 4;   // this wave's 4 batch elems

  // ---------------- q_sum ----------------
  {
    float m[4];
    gather4(x, we, Lws[0], 276, 10, b0, lane, m);
    #pragma unroll
    for (int j = 0; j < 4; ++j) cbuf[w][j][lane] = m[j];
  }

  // ---------------- LSTM streams ----------------
  const int sbase[4]  = {211, 662, 612, 397};
  const int srowsA[4] = {10, 5, 5, 10};
  const int sstr[4]   = {13, 10, 10, 13};

  for (int s = 0; s < 4; ++s) {
    float m[5][4];
    for (int t = 0; t < 5; ++t)
      gather4(x, we, Lws[1 + s*5 + t], sbase[s] + sstr[s]*t, srowsA[s], b0, lane, m[t]);

    float hreg[4], creg[4];
    #pragma unroll
    for (int j = 0; j < 4; ++j) {
      hreg[j] = h0[(size_t)(s*BN + b0 + j) * 64 + lane];
      creg[j] = c0[(size_t)(s*BN + b0 + j) * 64 + lane];
    }
    float bias[4];
    #pragma unroll
    for (int g = 0; g < 4; ++g)
      bias[g] = bih[s*256 + g*64 + lane] + bhh[s*256 + g*64 + lane];

    const float* wi = Wih + (size_t)s * 256 * 64;
    const float* wh = Whh + (size_t)s * 256 * 64;

    for (int t = 0; t < 5; ++t) {
      __syncthreads();
      #pragma unroll
      for (int j = 0; j < 4; ++j) {
        abuf[w][j][lane]      = m[t][j];
        abuf[w][j][64 + lane] = hreg[j];
      }
      __syncthreads();

      float acc[4][4];
      #pragma unroll
      for (int g = 0; g < 4; ++g)
        #pragma unroll
        for (int j = 0; j < 4; ++j) acc[g][j] = bias[g];

      #pragma unroll 4
      for (int kq = 0; kq < 16; ++kq) {
        const int k4 = kq * 4;
        float4 wx0 = ld4(wi + (size_t)(0*64 + lane)*64 + k4);
        float4 wx1 = ld4(wi + (size_t)(1*64 + lane)*64 + k4);
        float4 wx2 = ld4(wi + (size_t)(2*64 + lane)*64 + k4);
        float4 wx3 = ld4(wi + (size_t)(3*64 + lane)*64 + k4);
        float4 wg0 = ld4(wh + (size_t)(0*64 + lane)*64 + k4);
        float4 wg1 = ld4(wh + (size_t)(1*64 + lane)*64 + k4);
        float4 wg2 = ld4(wh + (size_t)(2*64 + lane)*64 + k4);
        float4 wg3 = ld4(wh + (size_t)(3*64 + lane)*64 + k4);
        #pragma unroll
        for (int j = 0; j < 4; ++j) {
          float4 xv = *(const float4*)&abuf[w][j][k4];
          float4 hv = *(const float4*)&abuf[w][j][64 + k4];
          acc[0][j] += dot4(wx0, xv) + dot4(wg0, hv);
          acc[1][j] += dot4(wx1, xv) + dot4(wg1, hv);
          acc[2][j] += dot4(wx2, xv) + dot4(wg2, hv);
          acc[3][j] += dot4(wx3, xv) + dot4(wg3, hv);
        }
      }
      #pragma unroll
      for (int j = 0; j < 4; ++j) {
        float ig = sig_(acc[0][j]);
        float fg = sig_(acc[1][j]);
        float gg = tanhf(acc[2][j]);
        float og = sig_(acc[3][j]);
        creg[j] = fg * creg[j] + ig * gg;
        hreg[j] = og * tanhf(creg[j]);
      }
    }

    // s_i = tanh(w_l[s] @ h.T + b_l[s])
    __syncthreads();
    #pragma unroll
    for (int j = 0; j < 4; ++j) abuf[w][j][64 + lane] = hreg[j];
    __syncthreads();
    float acc2[4];
    #pragma unroll
    for (int j = 0; j < 4; ++j) acc2[j] = bl[s*64 + lane];
    #pragma unroll 4
    for (int kq = 0; kq < 16; ++kq) {
      const int k4 = kq * 4;
      float4 wv = ld4(wl + (size_t)(s*64 + lane)*64 + k4);
      #pragma unroll
      for (int j = 0; j < 4; ++j)
        acc2[j] += dot4(wv, *(const float4*)&abuf[w][j][64 + k4]);
    }
    #pragma unroll
    for (int j = 0; j < 4; ++j)
      cbuf[w][j][(1 + s)*64 + lane] = tanhf(acc2[j]);
  }

  // ---------------- CNN streams ----------------
  for (int cs = 0; cs < 2; ++cs) {
    const float* cw = cs ? c2w : c1w;
    const float* cb = cs ? c2b : c1b;
    const float* lw = cs ? l2w : l1w;
    const float* lb = cs ? l2b : l1b;
    const int base0 = cs ? 862 : 512;
    const int chunk0 = 21 + cs * 5;

    for (int t = 0; t < 5; ++t) {
      float m[4];
      gather4(x, we, Lws[chunk0 + t], base0 + 10*t, 5, b0, lane, m);
      #pragma unroll
      for (int j = 0; j < 4; ++j) sbuf[w][j][t*64 + lane] = m[j];
    }
    __syncthreads();

    // conv (VALID over h: 5->4, kw covers full E=64): lane = o*4 + h, o<12
    const int o  = lane >> 2;
    const int hh = lane & 3;
    float cvo[4];
    #pragma unroll
    for (int j = 0; j < 4; ++j) {
      float a = 0.f;
      if (lane < 48) {
        a = cb[o];
        #pragma unroll
        for (int kh = 0; kh < 2; ++kh)
          #pragma unroll 4
          for (int kq = 0; kq < 16; ++kq) {
            const int k4 = kq * 4;
            float4 sv = *(const float4*)&sbuf[w][j][(hh + kh)*64 + k4];
            float4 cv = ld4(cw + (size_t)o*128 + kh*64 + k4);
            a += dot4(sv, cv);
          }
        a = fmaxf(a, 0.f);
      }
      cvo[j] = a;
    }
    __syncthreads();
    #pragma unroll
    for (int j = 0; j < 4; ++j) abuf[w][j][lane] = cvo[j];
    __syncthreads();

    // maxpool(2 over h) -> f[p*12+o]; then relu(f @ lw.T + lb)
    #pragma unroll
    for (int j = 0; j < 4; ++j) {
      float a = lb[lane];
      #pragma unroll
      for (int p = 0; p < 2; ++p)
        #pragma unroll
        for (int o2 = 0; o2 < 12; ++o2) {
          float f = fmaxf(abuf[w][j][o2*4 + 2*p], abuf[w][j][o2*4 + 2*p + 1]);
          a += lw[lane*24 + p*12 + o2] * f;
        }
      cbuf[w][j][(5 + cs)*64 + lane] = fmaxf(a, 0.f);
    }
  }

  // ---------------- wide ----------------
  float accw[4];
  #pragma unroll
  for (int j = 0; j < 4; ++j) accw[j] = wb[lane];
  for (int i = 0; i < 81; ++i) {
    float4 xv = ld4(x + (size_t)i * BN + b0);
    float wv = ww[lane*81 + i];
    accw[0] += wv * xv.x; accw[1] += wv * xv.y;
    accw[2] += wv * xv.z; accw[3] += wv * xv.w;
  }
  float widev[4];
  #pragma unroll
  for (int j = 0; j < 4; ++j) widev[j] = tanhf(accw[j]);

  // ---------------- q = tanh(cq_w @ concat + cq_b) ----------------
  __syncthreads();
  float accq[4];
  #pragma unroll
  for (int j = 0; j < 4; ++j) accq[j] = cqb[lane];
  #pragma unroll 4
  for (int kq = 0; kq < 112; ++kq) {
    const int k4 = kq * 4;
    float4 wv = ld4(cqw + (size_t)lane*448 + k4);
    #pragma unroll
    for (int j = 0; j < 4; ++j)
      accq[j] += dot4(wv, *(const float4*)&cbuf[w][j][k4]);
  }
  float qv[4];
  #pragma unroll
  for (int j = 0; j < 4; ++j) qv[j] = tanhf(accq[j]);

  // ---------------- qw = tanh(cqu_w @ [q; wide] + cqu_b) ----------------
  __syncthreads();
  #pragma unroll
  for (int j = 0; j < 4; ++j) {
    abuf[w][j][lane]      = qv[j];
    abuf[w][j][64 + lane] = widev[j];
  }
  __syncthreads();
  float accu[4];
  #pragma unroll
  for (int j = 0; j < 4; ++j) accu[j] = cqub[lane];
  #pragma unroll 4
  for (int kq = 0; kq < 32; ++kq) {
    const int k4 = kq * 4;
    float4 wv = ld4(cquw + (size_t)lane*128 + k4);
    #pragma unroll
    for (int j = 0; j < 4; ++j)
      accu[j] += dot4(wv, *(const float4*)&abuf[w][j][k4]);
  }

  // ---------------- out = dw_w @ qw + dw_b (wave reduce over lanes) ----------------
  float dwv = dww[lane];
  float pj[4];
  #pragma unroll
  for (int j = 0; j < 4; ++j) pj[j] = dwv * tanhf(accu[j]);
  #pragma unroll
  for (int off = 32; off > 0; off >>= 1)
    #pragma unroll
    for (int j = 0; j < 4; ++j) pj[j] += __shfl_down(pj[j], off);
  if (lane == 0) {
    float db = dwb[0];
    #pragma unroll
    for (int j = 0; j < 4; ++j) out[b0 + j] = pj[j] + db;
  }
}

extern "C" void kernel_launch(void* const* d_in, const int* in_sizes, int n_in,
                              void* d_out, int out_size, void* d_ws, size_t ws_size,
                              hipStream_t stream) {
  const float* x    = (const float*)d_in[0];
  const float* we   = (const float*)d_in[1];
  const float* Wih  = (const float*)d_in[2];
  const float* Whh  = (const float*)d_in[3];
  const float* bihp = (const float*)d_in[4];
  const float* bhhp = (const float*)d_in[5];
  const float* h0   = (const float*)d_in[6];
  const float* c0   = (const float*)d_in[7];
  const float* wl   = (const float*)d_in[8];
  const float* bl   = (const float*)d_in[9];
  const float* c1w  = (const float*)d_in[10];
  const float* c1b  = (const float*)d_in[11];
  const float* l1w  = (const float*)d_in[12];
  const float* l1b  = (const float*)d_in[13];
  const float* c2w  = (const float*)d_in[14];
  const float* c2b  = (const float*)d_in[15];
  const float* l2w  = (const float*)d_in[16];
  const float* l2b  = (const float*)d_in[17];
  const float* ww   = (const float*)d_in[18];
  const float* wb   = (const float*)d_in[19];
  const float* cqw  = (const float*)d_in[20];
  const float* cqb  = (const float*)d_in[21];
  const float* cquw = (const float*)d_in[22];
  const float* cqub = (const float*)d_in[23];
  const float* dww  = (const float*)d_in[24];
  const float* dwb  = (const float*)d_in[25];

  float* Lws = (float*)d_ws;   // 31 floats

  count_L_kernel<<<31, 256, 0, stream>>>(x, Lws);
  model_kernel<<<256, 256, 0, stream>>>(
      x, we, Wih, Whh, bihp, bhhp, h0, c0, wl, bl,
      c1w, c1b, l1w, l1b, c2w, c2b, l2w, l2b,
      ww, wb, cqw, cqb, cquw, cqub, dww, dwb,
      Lws, (float*)d_out);
}

// Round 2
// 386.183 us; speedup vs baseline: 2.1740x; 2.1740x over previous
//
#include <hip/hip_runtime.h>
#include <math.h>

#define BN 4096
typedef unsigned short u16;
typedef unsigned int   u32;
typedef short bfx8 __attribute__((ext_vector_type(8)));
typedef float fx4  __attribute__((ext_vector_type(4)));

// ---- chunk tables: (base row in x, rows used) for the 31 masked means ----
// 0: q_sum; 1..5: s1; 6..10: s2; 11..15: s3; 16..20: s4; 21..25: c1; 26..30: c2
__device__ const int c_base[31] = {
  276,
  211, 224, 237, 250, 263,
  662, 672, 682, 692, 702,
  612, 622, 632, 642, 652,
  397, 410, 423, 436, 449,
  512, 522, 532, 542, 552,
  862, 872, 882, 892, 902
};
__device__ const int c_rows[31] = {
  10,
  10,10,10,10,10,
  5,5,5,5,5,
  5,5,5,5,5,
  10,10,10,10,10,
  5,5,5,5,5,
  5,5,5,5,5
};

__device__ __forceinline__ u16 f2bf(float f){
  u32 u = __float_as_uint(f);
  return (u16)((u + 0x7FFFu + ((u >> 16) & 1u)) >> 16);   // RNE
}
__device__ __forceinline__ float bf2f(u16 h){ return __uint_as_float(((u32)h) << 16); }
__device__ __forceinline__ float4 ld4(const float* p){ return *(const float4*)p; }
__device__ __forceinline__ float dot4(float4 a, float4 b){
  return a.x*b.x + a.y*b.y + a.z*b.z + a.w*b.w;
}
__device__ __forceinline__ float sigf(float v){ return 1.0f / (1.0f + __expf(-v)); }

// ---- Kernel 1: sign-count partials (int, exact) ----
extern "C" __global__ __launch_bounds__(256)
void count_kernel(const float* __restrict__ x, int* __restrict__ cnt){
  __shared__ int red[256];
  const int c = blockIdx.x >> 3, part = blockIdx.x & 7;
  const int base = c_base[c], rows = c_rows[c];
  const int n_per = rows * 512;          // rows*4096/8
  const int start = part * n_per;
  int s = 0;
  for (int i = start + threadIdx.x; i < start + n_per; i += 256){
    float v = x[(size_t)(base + (i >> 12)) * BN + (i & 4095)];
    s += (v > 0.f) ? 1 : ((v < 0.f) ? -1 : 0);
  }
  red[threadIdx.x] = s; __syncthreads();
  for (int off = 128; off > 0; off >>= 1){
    if (threadIdx.x < off) red[threadIdx.x] += red[threadIdx.x + off];
    __syncthreads();
  }
  if (threadIdx.x == 0) atomicAdd(&cnt[c], red[0]);
}

// ---- Kernel 2: weight bf16 pre-conversion + bias sum ----
// Wcb[s][256 gates][128 k] (k<64: Wih, k>=64: Whh); wlb[s][64][64]; bias_sum[s][256]
extern "C" __global__ __launch_bounds__(256)
void prep_kernel(const float* __restrict__ Wih, const float* __restrict__ Whh,
                 const float* __restrict__ wl,  const float* __restrict__ bih,
                 const float* __restrict__ bhh,
                 u16* __restrict__ Wcb, u16* __restrict__ wlb, float* __restrict__ bias_sum){
  int idx = blockIdx.x * 256 + threadIdx.x;
  if (idx < 131072){
    int s = idx >> 15, rem = idx & 32767, n = rem >> 7, k = rem & 127;
    float v = (k < 64) ? Wih[s*16384 + n*64 + k] : Whh[s*16384 + n*64 + (k-64)];
    Wcb[idx] = f2bf(v);
  } else if (idx < 147456){
    int j = idx - 131072;                 // same [4][64][64] layout
    wlb[j] = f2bf(wl[j]);
  } else if (idx < 148480){
    int j = idx - 147456;
    bias_sum[j] = bih[j] + bhh[j];
  }
}

// masked-mean gather for 4 consecutive batch elems; lane = embed dim (coalesced)
__device__ __forceinline__ void gather4(const float* __restrict__ x,
                                        const float* __restrict__ we,
                                        float L, int base, int rows,
                                        int b0, int lane, float* m) {
  float a0 = 0.f, a1 = 0.f, a2 = 0.f, a3 = 0.f;
  for (int r = 0; r < rows; ++r) {
    if ((float)r < L) {           // uniform branch (L is a global scalar)
      float4 iv = ld4(x + (size_t)(base + r) * BN + b0);
      a0 += we[(size_t)(int)iv.x * 64 + lane];
      a1 += we[(size_t)(int)iv.y * 64 + lane];
      a2 += we[(size_t)(int)iv.z * 64 + lane];
      a3 += we[(size_t)(int)iv.w * 64 + lane];
    }
  }
  m[0] = a0 / L; m[1] = a1 / L; m[2] = a2 / L; m[3] = a3 / L;
}

// ---- Kernel 3: all 31 masked means -> Mbf[c][4096][64] bf16 ----
extern "C" __global__ __launch_bounds__(256)
void means_kernel(const float* __restrict__ x, const float* __restrict__ we,
                  const int* __restrict__ cnt, u16* __restrict__ Mbf){
  const int c = blockIdx.x >> 8, tile = blockIdx.x & 255;
  const int w = threadIdx.x >> 6, lane = threadIdx.x & 63;
  const int b0 = tile * 16 + w * 4;
  const int base = c_base[c], rows = c_rows[c];
  const float L = fminf(fmaxf((float)cnt[c], 1.f), (float)rows);
  float m[4];
  gather4(x, we, L, base, rows, b0, lane, m);
  #pragma unroll
  for (int j = 0; j < 4; ++j)
    Mbf[((size_t)c * BN + b0 + j) * 64 + lane] = f2bf(m[j]);
}

// ---- Kernel 4: LSTM streams via bf16 MFMA ----
// Block: (stream st, 64-batch tile). GEMM C[256 gate][64 batch] = Wc[256][128] @ Xh^T.
// Wave w owns batch cols 16w..16w+15 (lane&15 = batch, lane>>4 = quad -> k / m-rows).
// Lane holds all 4 gates for its (b,d): acc[mt=t*4+dc][r] -> gate t, d=dc*16+quad*4+r.
extern "C" __global__ __launch_bounds__(256, 1)
void lstm_kernel(const u16* __restrict__ Wcb, const u16* __restrict__ wlb,
                 const float* __restrict__ bias_sum, const u16* __restrict__ Mbf,
                 const float* __restrict__ h0, const float* __restrict__ c0,
                 const float* __restrict__ bl, float* __restrict__ S){
  __shared__ u16 Xh[64][136];   // [batch row][k: 0..63 x_t, 64..127 h], padded

  const int tid = threadIdx.x, w = tid >> 6, lane = tid & 63;
  const int quad = lane >> 4, l0 = lane & 15;
  const int st = blockIdx.x & 3, tile = blockIdx.x >> 2, b0 = tile * 64;
  const int brow = 16 * w + l0;                 // this lane's batch row in tile
  const u16* Wc = Wcb + (size_t)st * 32768;

  // biases (per-lane float4 per m-tile), c-state in regs
  fx4 bias4[16];
  #pragma unroll
  for (int mt = 0; mt < 16; ++mt)
    bias4[mt] = *(const fx4*)(bias_sum + st*256 + mt*16 + quad*4);

  float cst[4][4];
  #pragma unroll
  for (int dc = 0; dc < 4; ++dc){
    float4 v = ld4(c0 + ((size_t)st*BN + b0 + brow)*64 + dc*16 + quad*4);
    cst[dc][0]=v.x; cst[dc][1]=v.y; cst[dc][2]=v.z; cst[dc][3]=v.w;
  }
  // stage h0 (bf16) into Xh[brow][64..127]; quads partition d
  {
    const float* hp = h0 + ((size_t)st*BN + b0 + brow)*64 + quad*16;
    #pragma unroll
    for (int i = 0; i < 4; ++i){
      float4 v = ld4(hp + i*4);
      u32* dst = (u32*)&Xh[brow][64 + quad*16 + i*4];
      dst[0] = (u32)f2bf(v.x) | ((u32)f2bf(v.y) << 16);
      dst[1] = (u32)f2bf(v.z) | ((u32)f2bf(v.w) << 16);
    }
  }

  for (int t = 0; t < 5; ++t){
    // stage x_t from Mbf (already bf16): 32 B per lane
    {
      const u16* src = Mbf + ((size_t)(1 + st*5 + t)*BN + b0 + brow)*64 + quad*16;
      *(uint4*)&Xh[brow][quad*16]     = *(const uint4*)src;
      *(uint4*)&Xh[brow][quad*16 + 8] = *(const uint4*)(src + 8);
    }
    __syncthreads();

    fx4 acc[16];
    #pragma unroll
    for (int mt = 0; mt < 16; ++mt) acc[mt] = bias4[mt];
    #pragma unroll
    for (int kc = 0; kc < 4; ++kc){
      bfx8 bfr = *(const bfx8*)&Xh[brow][kc*32 + quad*8];          // B[k][n=b]
      #pragma unroll
      for (int mt = 0; mt < 16; ++mt){
        bfx8 afr = *(const bfx8*)(Wc + (size_t)(mt*16 + l0)*128 + kc*32 + quad*8); // A[m=g][k]
        acc[mt] = __builtin_amdgcn_mfma_f32_16x16x32_bf16(afr, bfr, acc[mt], 0, 0, 0);
      }
    }
    // elementwise gate update, all in-lane
    #pragma unroll
    for (int dc = 0; dc < 4; ++dc){
      u16 hv[4];
      #pragma unroll
      for (int r = 0; r < 4; ++r){
        float ig = sigf(acc[dc][r]);
        float fg = sigf(acc[4 + dc][r]);
        float gg = tanhf(acc[8 + dc][r]);
        float og = sigf(acc[12 + dc][r]);
        float cc = fg * cst[dc][r] + ig * gg;
        cst[dc][r] = cc;
        hv[r] = f2bf(og * tanhf(cc));
      }
      u32* dst = (u32*)&Xh[brow][64 + dc*16 + quad*4];
      dst[0] = (u32)hv[0] | ((u32)hv[1] << 16);
      dst[1] = (u32)hv[2] | ((u32)hv[3] << 16);
    }
    __syncthreads();
  }

  // S_st = tanh(w_l @ h^T + b_l): C2[64 d][64 b], A = wlb rows, B = h from Xh
  fx4 acc2[4];
  #pragma unroll
  for (int mt = 0; mt < 4; ++mt){ acc2[mt].x=0.f; acc2[mt].y=0.f; acc2[mt].z=0.f; acc2[mt].w=0.f; }
  #pragma unroll
  for (int kc = 0; kc < 2; ++kc){
    bfx8 bfr = *(const bfx8*)&Xh[brow][64 + kc*32 + quad*8];
    #pragma unroll
    for (int mt = 0; mt < 4; ++mt){
      bfx8 afr = *(const bfx8*)(wlb + (size_t)st*4096 + (size_t)(mt*16 + l0)*64 + kc*32 + quad*8);
      acc2[mt] = __builtin_amdgcn_mfma_f32_16x16x32_bf16(afr, bfr, acc2[mt], 0, 0, 0);
    }
  }
  #pragma unroll
  for (int mt = 0; mt < 4; ++mt){
    fx4 blv = *(const fx4*)(bl + st*64 + mt*16 + quad*4);
    fx4 o;
    o.x = tanhf(acc2[mt].x + blv.x);
    o.y = tanhf(acc2[mt].y + blv.y);
    o.z = tanhf(acc2[mt].z + blv.z);
    o.w = tanhf(acc2[mt].w + blv.w);
    *(fx4*)(S + ((size_t)st*BN + b0 + brow)*64 + mt*16 + quad*4) = o;
  }
}

// ---- Kernel 5: CNN + wide + concat cascade. 1 batch per wave, grid 1024. ----
extern "C" __global__ __launch_bounds__(256)
void final_kernel(
    const float* __restrict__ x,   const u16* __restrict__ Mbf,
    const float* __restrict__ S,
    const float* __restrict__ c1w, const float* __restrict__ c1b,
    const float* __restrict__ l1w, const float* __restrict__ l1b,
    const float* __restrict__ c2w, const float* __restrict__ c2b,
    const float* __restrict__ l2w, const float* __restrict__ l2b,
    const float* __restrict__ ww,  const float* __restrict__ wb,
    const float* __restrict__ cqw, const float* __restrict__ cqb,
    const float* __restrict__ cquw,const float* __restrict__ cqub,
    const float* __restrict__ dww, const float* __restrict__ dwb,
    float* __restrict__ out)
{
  __shared__ __align__(16) float cbuf[4][448];
  __shared__ __align__(16) float sbuf[4][320];
  __shared__ __align__(16) float abuf[4][128];

  const int tid = threadIdx.x, w = tid >> 6, lane = tid & 63;
  const int b = blockIdx.x * 4 + w;

  // q_sum + LSTM stream outputs into concat buffer
  cbuf[w][lane] = bf2f(Mbf[(size_t)b * 64 + lane]);
  #pragma unroll
  for (int s = 0; s < 4; ++s)
    cbuf[w][64 + s*64 + lane] = S[((size_t)s*BN + b)*64 + lane];

  // CNN streams
  for (int cs = 0; cs < 2; ++cs){
    const float* cw = cs ? c2w : c1w;
    const float* cb = cs ? c2b : c1b;
    const float* lw = cs ? l2w : l1w;
    const float* lb = cs ? l2b : l1b;
    const int chunk0 = 21 + cs * 5;

    #pragma unroll
    for (int t = 0; t < 5; ++t)
      sbuf[w][t*64 + lane] = bf2f(Mbf[((size_t)(chunk0 + t)*BN + b)*64 + lane]);
    __syncthreads();

    const int o  = lane >> 2;
    const int hh = lane & 3;
    float a = 0.f;
    if (lane < 48){
      a = cb[o];
      #pragma unroll
      for (int kh = 0; kh < 2; ++kh)
        #pragma unroll 4
        for (int kq = 0; kq < 16; ++kq){
          const int k4 = kq * 4;
          float4 sv = *(const float4*)&sbuf[w][(hh + kh)*64 + k4];
          float4 cv = ld4(cw + (size_t)o*128 + kh*64 + k4);
          a += dot4(sv, cv);
        }
      a = fmaxf(a, 0.f);
    }
    __syncthreads();
    abuf[w][lane] = a;
    __syncthreads();

    float a2 = lb[lane];
    #pragma unroll
    for (int p = 0; p < 2; ++p)
      #pragma unroll
      for (int o2 = 0; o2 < 12; ++o2){
        float f = fmaxf(abuf[w][o2*4 + 2*p], abuf[w][o2*4 + 2*p + 1]);
        a2 += lw[lane*24 + p*12 + o2] * f;
      }
    cbuf[w][(5 + cs)*64 + lane] = fmaxf(a2, 0.f);
    __syncthreads();
  }

  // wide
  float accw = wb[lane];
  for (int i = 0; i < 81; ++i)
    accw += ww[lane*81 + i] * x[(size_t)i * BN + b];
  float widev = tanhf(accw);

  __syncthreads();
  // q = tanh(cq_w @ concat + cq_b)
  float accq = cqb[lane];
  #pragma unroll 4
  for (int kq = 0; kq < 112; ++kq){
    const int k4 = kq * 4;
    accq += dot4(ld4(cqw + (size_t)lane*448 + k4), *(const float4*)&cbuf[w][k4]);
  }
  float qv = tanhf(accq);

  __syncthreads();
  abuf[w][lane]      = qv;
  abuf[w][64 + lane] = widev;
  __syncthreads();

  float accu = cqub[lane];
  #pragma unroll 4
  for (int kq = 0; kq < 32; ++kq){
    const int k4 = kq * 4;
    accu += dot4(ld4(cquw + (size_t)lane*128 + k4), *(const float4*)&abuf[w][k4]);
  }

  float pj = dww[lane] * tanhf(accu);
  #pragma unroll
  for (int off = 32; off > 0; off >>= 1) pj += __shfl_down(pj, off);
  if (lane == 0) out[b] = pj + dwb[0];
}

extern "C" void kernel_launch(void* const* d_in, const int* in_sizes, int n_in,
                              void* d_out, int out_size, void* d_ws, size_t ws_size,
                              hipStream_t stream) {
  const float* x    = (const float*)d_in[0];
  const float* we   = (const float*)d_in[1];
  const float* Wih  = (const float*)d_in[2];
  const float* Whh  = (const float*)d_in[3];
  const float* bihp = (const float*)d_in[4];
  const float* bhhp = (const float*)d_in[5];
  const float* h0   = (const float*)d_in[6];
  const float* c0   = (const float*)d_in[7];
  const float* wl   = (const float*)d_in[8];
  const float* bl   = (const float*)d_in[9];
  const float* c1w  = (const float*)d_in[10];
  const float* c1b  = (const float*)d_in[11];
  const float* l1w  = (const float*)d_in[12];
  const float* l1b  = (const float*)d_in[13];
  const float* c2w  = (const float*)d_in[14];
  const float* c2b  = (const float*)d_in[15];
  const float* l2w  = (const float*)d_in[16];
  const float* l2b  = (const float*)d_in[17];
  const float* ww   = (const float*)d_in[18];
  const float* wb   = (const float*)d_in[19];
  const float* cqw  = (const float*)d_in[20];
  const float* cqb  = (const float*)d_in[21];
  const float* cquw = (const float*)d_in[22];
  const float* cqub = (const float*)d_in[23];
  const float* dww  = (const float*)d_in[24];
  const float* dwb  = (const float*)d_in[25];

  char* ws = (char*)d_ws;
  int*   cnt  = (int*)ws;                        // 31 ints
  u16*   Mbf  = (u16*)(ws + 1024);               // 31*4096*64 bf16 = 16,252,928 B
  u16*   Wcb  = (u16*)(ws + 16253952);           // 4*256*128 bf16  = 262,144 B
  u16*   wlb  = (u16*)(ws + 16516096);           // 4*64*64 bf16    = 32,768 B
  float* bias = (float*)(ws + 16548864);         // 4*256 f32       = 4,096 B
  float* S    = (float*)(ws + 16552960);         // 4*4096*64 f32   = 4,194,304 B

  hipMemsetAsync(cnt, 0, 31 * sizeof(int), stream);
  count_kernel<<<248, 256, 0, stream>>>(x, cnt);
  prep_kernel<<<580, 256, 0, stream>>>(Wih, Whh, wl, bihp, bhhp, Wcb, wlb, bias);
  means_kernel<<<7936, 256, 0, stream>>>(x, we, cnt, Mbf);
  lstm_kernel<<<256, 256, 0, stream>>>(Wcb, wlb, bias, Mbf, h0, c0, bl, S);
  final_kernel<<<1024, 256, 0, stream>>>(x, Mbf, S,
      c1w, c1b, l1w, l1b, c2w, c2b, l2w, l2b,
      ww, wb, cqw, cqb, cquw, cqub, dww, dwb, (float*)d_out);
}

// Round 3
// 354.560 us; speedup vs baseline: 2.3679x; 1.0892x over previous
//
#include <hip/hip_runtime.h>
#include <math.h>

#define BN 4096
typedef unsigned short u16;
typedef unsigned int   u32;
typedef short bfx8 __attribute__((ext_vector_type(8)));
typedef float fx4  __attribute__((ext_vector_type(4)));

// ---- chunk tables: (base row in x, rows used) for the 31 masked means ----
__device__ const int c_base[31] = {
  276,
  211, 224, 237, 250, 263,
  662, 672, 682, 692, 702,
  612, 622, 632, 642, 652,
  397, 410, 423, 436, 449,
  512, 522, 532, 542, 552,
  862, 872, 882, 892, 902
};
__device__ const int c_rows[31] = {
  10,
  10,10,10,10,10,
  5,5,5,5,5,
  5,5,5,5,5,
  10,10,10,10,10,
  5,5,5,5,5,
  5,5,5,5,5
};

__device__ __forceinline__ u16 f2bf(float f){
  u32 u = __float_as_uint(f);
  return (u16)((u + 0x7FFFu + ((u >> 16) & 1u)) >> 16);   // RNE
}
__device__ __forceinline__ float bf2f(u16 h){ return __uint_as_float(((u32)h) << 16); }
__device__ __forceinline__ float4 ld4(const float* p){ return *(const float4*)p; }
__device__ __forceinline__ float sigf(float v){ return 1.0f / (1.0f + __expf(-v)); }

// ---- Kernel 1: count partials (blocks 0..247) + weight prep (blocks 248..1004) ----
extern "C" __global__ __launch_bounds__(256)
void setup_kernel(const float* __restrict__ x, int* __restrict__ cnt,
                  const float* __restrict__ Wih, const float* __restrict__ Whh,
                  const float* __restrict__ wl,  const float* __restrict__ bih,
                  const float* __restrict__ bhh,
                  const float* __restrict__ cqw, const float* __restrict__ cquw,
                  const float* __restrict__ ww,  const float* __restrict__ l1w,
                  const float* __restrict__ l2w,
                  u16* __restrict__ Wcb, u16* __restrict__ wlb,
                  float* __restrict__ bias_sum,
                  float* __restrict__ cqwT, float* __restrict__ cquwT,
                  float* __restrict__ wwT,  float* __restrict__ lwT){
  __shared__ int red[256];
  if (blockIdx.x < 248){
    const int c = blockIdx.x >> 3, part = blockIdx.x & 7;
    const int base = c_base[c], rows = c_rows[c];
    const int n_per = rows * 512;
    const int start = part * n_per;
    int s = 0;
    for (int i = start + threadIdx.x; i < start + n_per; i += 256){
      float v = x[(size_t)(base + (i >> 12)) * BN + (i & 4095)];
      s += (v > 0.f) ? 1 : ((v < 0.f) ? -1 : 0);
    }
    red[threadIdx.x] = s; __syncthreads();
    for (int off = 128; off > 0; off >>= 1){
      if (threadIdx.x < off) red[threadIdx.x] += red[threadIdx.x + off];
      __syncthreads();
    }
    if (threadIdx.x == 0) atomicAdd(&cnt[c], red[0]);
    return;
  }
  int idx = (blockIdx.x - 248) * 256 + threadIdx.x;
  if (idx < 131072){
    int s = idx >> 15, rem = idx & 32767, n = rem >> 7, k = rem & 127;
    float v = (k < 64) ? Wih[s*16384 + n*64 + k] : Whh[s*16384 + n*64 + (k-64)];
    Wcb[idx] = f2bf(v);
  } else if (idx < 147456){
    int j = idx - 131072;
    wlb[j] = f2bf(wl[j]);
  } else if (idx < 148480){
    int j = idx - 147456;
    bias_sum[j] = bih[j] + bhh[j];
  } else if (idx < 177152){
    int j = idx - 148480;                    // cqwT[448][64]
    int k = j >> 6, m = j & 63;
    cqwT[j] = cqw[m*448 + k];
  } else if (idx < 185344){
    int j = idx - 177152;                    // cquwT[128][64]
    int k = j >> 6, m = j & 63;
    cquwT[j] = cquw[m*128 + k];
  } else if (idx < 190528){
    int j = idx - 185344;                    // wwT[81][64]
    int k = j >> 6, m = j & 63;
    wwT[j] = ww[m*81 + k];
  } else if (idx < 193600){
    int j = idx - 190528;                    // lwT[2][24][64]
    int cs = j >= 1536;
    int r = j - (cs ? 1536 : 0);
    int k = r >> 6, m = r & 63;
    lwT[j] = (cs ? l2w : l1w)[m*24 + k];
  }
}

// ---- Kernel 2: all 31 masked means -> Mbf[c][4096][64] bf16 ----
// Fully unrolled gather (ROWS compile-time): all index loads + gathers in flight.
// Indices are always valid (x in [0,V)), so gather unconditionally and mask.
template<int ROWS>
__device__ __forceinline__ void means_body(const float* __restrict__ x,
                                           const float* __restrict__ we,
                                           float L, int base, int b0, int lane,
                                           float* m){
  float a0 = 0.f, a1 = 0.f, a2 = 0.f, a3 = 0.f;
  #pragma unroll
  for (int r = 0; r < ROWS; ++r){
    float4 iv = ld4(x + (size_t)(base + r) * BN + b0);
    float wr = ((float)r < L) ? 1.f : 0.f;
    a0 += wr * we[(size_t)(int)iv.x * 64 + lane];
    a1 += wr * we[(size_t)(int)iv.y * 64 + lane];
    a2 += wr * we[(size_t)(int)iv.z * 64 + lane];
    a3 += wr * we[(size_t)(int)iv.w * 64 + lane];
  }
  m[0] = a0 / L; m[1] = a1 / L; m[2] = a2 / L; m[3] = a3 / L;
}

extern "C" __global__ __launch_bounds__(256)
void means_kernel(const float* __restrict__ x, const float* __restrict__ we,
                  const int* __restrict__ cnt, u16* __restrict__ Mbf){
  const int c = blockIdx.x >> 8, tile = blockIdx.x & 255;
  const int w = threadIdx.x >> 6, lane = threadIdx.x & 63;
  const int b0 = tile * 16 + w * 4;
  const int base = c_base[c], rows = c_rows[c];
  const float L = fminf(fmaxf((float)cnt[c], 1.f), (float)rows);
  float m[4];
  if (rows == 5) means_body<5>(x, we, L, base, b0, lane, m);
  else          means_body<10>(x, we, L, base, b0, lane, m);
  #pragma unroll
  for (int j = 0; j < 4; ++j)
    Mbf[((size_t)c * BN + b0 + j) * 64 + lane] = f2bf(m[j]);
}

// ---- Kernel 3: LSTM streams via bf16 MFMA (unchanged from round 2) ----
extern "C" __global__ __launch_bounds__(256, 1)
void lstm_kernel(const u16* __restrict__ Wcb, const u16* __restrict__ wlb,
                 const float* __restrict__ bias_sum, const u16* __restrict__ Mbf,
                 const float* __restrict__ h0, const float* __restrict__ c0,
                 const float* __restrict__ bl, float* __restrict__ S){
  __shared__ u16 Xh[64][136];

  const int tid = threadIdx.x, w = tid >> 6, lane = tid & 63;
  const int quad = lane >> 4, l0 = lane & 15;
  const int st = blockIdx.x & 3, tile = blockIdx.x >> 2, b0 = tile * 64;
  const int brow = 16 * w + l0;
  const u16* Wc = Wcb + (size_t)st * 32768;

  fx4 bias4[16];
  #pragma unroll
  for (int mt = 0; mt < 16; ++mt)
    bias4[mt] = *(const fx4*)(bias_sum + st*256 + mt*16 + quad*4);

  float cst[4][4];
  #pragma unroll
  for (int dc = 0; dc < 4; ++dc){
    float4 v = ld4(c0 + ((size_t)st*BN + b0 + brow)*64 + dc*16 + quad*4);
    cst[dc][0]=v.x; cst[dc][1]=v.y; cst[dc][2]=v.z; cst[dc][3]=v.w;
  }
  {
    const float* hp = h0 + ((size_t)st*BN + b0 + brow)*64 + quad*16;
    #pragma unroll
    for (int i = 0; i < 4; ++i){
      float4 v = ld4(hp + i*4);
      u32* dst = (u32*)&Xh[brow][64 + quad*16 + i*4];
      dst[0] = (u32)f2bf(v.x) | ((u32)f2bf(v.y) << 16);
      dst[1] = (u32)f2bf(v.z) | ((u32)f2bf(v.w) << 16);
    }
  }

  for (int t = 0; t < 5; ++t){
    {
      const u16* src = Mbf + ((size_t)(1 + st*5 + t)*BN + b0 + brow)*64 + quad*16;
      *(uint4*)&Xh[brow][quad*16]     = *(const uint4*)src;
      *(uint4*)&Xh[brow][quad*16 + 8] = *(const uint4*)(src + 8);
    }
    __syncthreads();

    fx4 acc[16];
    #pragma unroll
    for (int mt = 0; mt < 16; ++mt) acc[mt] = bias4[mt];
    #pragma unroll
    for (int kc = 0; kc < 4; ++kc){
      bfx8 bfr = *(const bfx8*)&Xh[brow][kc*32 + quad*8];
      #pragma unroll
      for (int mt = 0; mt < 16; ++mt){
        bfx8 afr = *(const bfx8*)(Wc + (size_t)(mt*16 + l0)*128 + kc*32 + quad*8);
        acc[mt] = __builtin_amdgcn_mfma_f32_16x16x32_bf16(afr, bfr, acc[mt], 0, 0, 0);
      }
    }
    #pragma unroll
    for (int dc = 0; dc < 4; ++dc){
      u16 hv[4];
      #pragma unroll
      for (int r = 0; r < 4; ++r){
        float ig = sigf(acc[dc][r]);
        float fg = sigf(acc[4 + dc][r]);
        float gg = tanhf(acc[8 + dc][r]);
        float og = sigf(acc[12 + dc][r]);
        float cc = fg * cst[dc][r] + ig * gg;
        cst[dc][r] = cc;
        hv[r] = f2bf(og * tanhf(cc));
      }
      u32* dst = (u32*)&Xh[brow][64 + dc*16 + quad*4];
      dst[0] = (u32)hv[0] | ((u32)hv[1] << 16);
      dst[1] = (u32)hv[2] | ((u32)hv[3] << 16);
    }
    __syncthreads();
  }

  fx4 acc2[4];
  #pragma unroll
  for (int mt = 0; mt < 4; ++mt){ acc2[mt].x=0.f; acc2[mt].y=0.f; acc2[mt].z=0.f; acc2[mt].w=0.f; }
  #pragma unroll
  for (int kc = 0; kc < 2; ++kc){
    bfx8 bfr = *(const bfx8*)&Xh[brow][64 + kc*32 + quad*8];
    #pragma unroll
    for (int mt = 0; mt < 4; ++mt){
      bfx8 afr = *(const bfx8*)(wlb + (size_t)st*4096 + (size_t)(mt*16 + l0)*64 + kc*32 + quad*8);
      acc2[mt] = __builtin_amdgcn_mfma_f32_16x16x32_bf16(afr, bfr, acc2[mt], 0, 0, 0);
    }
  }
  #pragma unroll
  for (int mt = 0; mt < 4; ++mt){
    fx4 blv = *(const fx4*)(bl + st*64 + mt*16 + quad*4);
    fx4 o;
    o.x = tanhf(acc2[mt].x + blv.x);
    o.y = tanhf(acc2[mt].y + blv.y);
    o.z = tanhf(acc2[mt].z + blv.z);
    o.w = tanhf(acc2[mt].w + blv.w);
    *(fx4*)(S + ((size_t)st*BN + b0 + brow)*64 + mt*16 + quad*4) = o;
  }
}

// ---- Kernel 4: tail. Block = 8 batch, thread = (b = tid&7, mg = tid>>3).
// All weight reads are lane-contiguous over mg (1 line/wave, broadcast over b);
// activations in LDS [k][b] (8-bank broadcast reads). Pure fp32.
extern "C" __global__ __launch_bounds__(256)
void final_kernel(
    const float* __restrict__ x,   const u16* __restrict__ Mbf,
    const float* __restrict__ S,
    const float* __restrict__ c1w, const float* __restrict__ c1b,
    const float* __restrict__ c2w, const float* __restrict__ c2b,
    const float* __restrict__ l1b, const float* __restrict__ l2b,
    const float* __restrict__ wwT, const float* __restrict__ wb,
    const float* __restrict__ cqwT,const float* __restrict__ cqb,
    const float* __restrict__ cquwT,const float* __restrict__ cqub,
    const float* __restrict__ lwT, const float* __restrict__ dww,
    const float* __restrict__ dwb, float* __restrict__ out)
{
  __shared__ float cb[448][9];     // concat [k][b]
  __shared__ float qwin[128][9];   // [q;wide] [k][b]
  __shared__ float sm[5][64][9];   // CNN step means [t][e][b]
  __shared__ float co[48][9];      // conv outs [o*4+h][b]
  __shared__ float cwS[12][130];   // staged conv weights [o][kh*64+e]
  __shared__ float red[32][8];

  const int tid = threadIdx.x;
  const int b   = tid & 7;
  const int mg  = tid >> 3;        // 0..31, owns outputs m = 2mg, 2mg+1
  const int b0  = blockIdx.x * 8;

  // ---- stage q_sum + LSTM outputs into concat ----
  {
    const int e = tid & 63, rr = tid >> 6;
    #pragma unroll
    for (int i = 0; i < 2; ++i){
      const int bb = rr*2 + i;
      cb[e][bb] = bf2f(Mbf[(size_t)(b0 + bb)*64 + e]);
      #pragma unroll
      for (int s = 0; s < 4; ++s)
        cb[64 + s*64 + e][bb] = S[((size_t)s*BN + b0 + bb)*64 + e];
    }
  }

  // ---- wide (fp32, exact): outputs into qwin[64..127] ----
  {
    float a0 = wb[mg*2], a1 = wb[mg*2+1];
    #pragma unroll 4
    for (int k = 0; k < 81; ++k){
      float xv = x[(size_t)k*BN + b0 + b];
      float2 wv = *(const float2*)(wwT + k*64 + mg*2);
      a0 += wv.x * xv; a1 += wv.y * xv;
    }
    qwin[64 + mg*2][b]     = tanhf(a0);
    qwin[64 + mg*2 + 1][b] = tanhf(a1);
  }

  // ---- CNN streams ----
  for (int cs = 0; cs < 2; ++cs){
    const float* cw    = cs ? c2w : c1w;
    const float* cbias = cs ? c2b : c1b;
    const float* lb    = cs ? l2b : l1b;

    __syncthreads();   // previous-iteration readers of sm/co done
    {
      const int e = tid & 63, rr = tid >> 6;
      #pragma unroll
      for (int t = 0; t < 5; ++t)
        #pragma unroll
        for (int i = 0; i < 2; ++i){
          const int bb = rr*2 + i;
          sm[t][e][bb] = bf2f(Mbf[((size_t)(21 + cs*5 + t)*BN + b0 + bb)*64 + e]);
        }
      for (int r2 = tid; r2 < 1536; r2 += 256){
        const int o = r2 >> 7, j = r2 & 127;
        cwS[o][j] = cw[o*128 + j];
      }
    }
    __syncthreads();

    // conv: og<24 active: o = og>>1, h in {2*(og&1), 2*(og&1)+1}
    if (mg < 24){
      const int o = mg >> 1, hb = (mg & 1) * 2;
      float a0 = cbias[o], a1 = cbias[o];
      #pragma unroll 4
      for (int e = 0; e < 64; ++e){
        float w0 = cwS[o][e], w1 = cwS[o][64 + e];
        float s0 = sm[hb][e][b], s1 = sm[hb+1][e][b], s2 = sm[hb+2][e][b];
        a0 += w0*s0 + w1*s1;
        a1 += w0*s1 + w1*s2;
      }
      co[o*4 + hb][b]     = fmaxf(a0, 0.f);
      co[o*4 + hb + 1][b] = fmaxf(a1, 0.f);
    }
    __syncthreads();

    // maxpool + linear: f[p*12+o]
    {
      float a0 = lb[mg*2], a1 = lb[mg*2+1];
      #pragma unroll
      for (int k = 0; k < 24; ++k){
        const int p = k >= 12, o = k - (p ? 12 : 0);
        float f = fmaxf(co[o*4 + 2*p][b], co[o*4 + 2*p + 1][b]);
        float2 lv = *(const float2*)(lwT + (cs*24 + k)*64 + mg*2);
        a0 += lv.x * f; a1 += lv.y * f;
      }
      cb[320 + cs*64 + mg*2][b]     = fmaxf(a0, 0.f);
      cb[320 + cs*64 + mg*2 + 1][b] = fmaxf(a1, 0.f);
    }
  }

  __syncthreads();
  // ---- q = tanh(cq_w @ concat + cq_b) ----
  {
    float a0 = cqb[mg*2], a1 = cqb[mg*2+1];
    #pragma unroll 8
    for (int k = 0; k < 448; ++k){
      float a = cb[k][b];
      float2 wv = *(const float2*)(cqwT + k*64 + mg*2);
      a0 += wv.x * a; a1 += wv.y * a;
    }
    qwin[mg*2][b]     = tanhf(a0);
    qwin[mg*2 + 1][b] = tanhf(a1);
  }
  __syncthreads();
  // ---- qw + dw ----
  {
    float a0 = cqub[mg*2], a1 = cqub[mg*2+1];
    #pragma unroll 8
    for (int k = 0; k < 128; ++k){
      float a = qwin[k][b];
      float2 wv = *(const float2*)(cquwT + k*64 + mg*2);
      a0 += wv.x * a; a1 += wv.y * a;
    }
    float2 dv = *(const float2*)(dww + mg*2);
    red[mg][b] = dv.x * tanhf(a0) + dv.y * tanhf(a1);
  }
  __syncthreads();
  if (tid < 8){
    float s = dwb[0];
    #pragma unroll 8
    for (int g = 0; g < 32; ++g) s += red[g][tid];
    out[b0 + tid] = s;
  }
}

extern "C" void kernel_launch(void* const* d_in, const int* in_sizes, int n_in,
                              void* d_out, int out_size, void* d_ws, size_t ws_size,
                              hipStream_t stream) {
  const float* x    = (const float*)d_in[0];
  const float* we   = (const float*)d_in[1];
  const float* Wih  = (const float*)d_in[2];
  const float* Whh  = (const float*)d_in[3];
  const float* bihp = (const float*)d_in[4];
  const float* bhhp = (const float*)d_in[5];
  const float* h0   = (const float*)d_in[6];
  const float* c0   = (const float*)d_in[7];
  const float* wl   = (const float*)d_in[8];
  const float* bl   = (const float*)d_in[9];
  const float* c1w  = (const float*)d_in[10];
  const float* c1b  = (const float*)d_in[11];
  const float* l1w  = (const float*)d_in[12];
  const float* l1b  = (const float*)d_in[13];
  const float* c2w  = (const float*)d_in[14];
  const float* c2b  = (const float*)d_in[15];
  const float* l2w  = (const float*)d_in[16];
  const float* l2b  = (const float*)d_in[17];
  const float* ww   = (const float*)d_in[18];
  const float* wb   = (const float*)d_in[19];
  const float* cqw  = (const float*)d_in[20];
  const float* cqb  = (const float*)d_in[21];
  const float* cquw = (const float*)d_in[22];
  const float* cqub = (const float*)d_in[23];
  const float* dww  = (const float*)d_in[24];
  const float* dwb  = (const float*)d_in[25];

  char* ws = (char*)d_ws;
  int*   cnt   = (int*)ws;                      // 124 B (pad to 1024)
  u16*   Mbf   = (u16*)(ws + 1024);             // 16,252,928
  u16*   Wcb   = (u16*)(ws + 16253952);         // 262,144
  u16*   wlb   = (u16*)(ws + 16516096);         // 32,768
  float* bias  = (float*)(ws + 16548864);       // 4,096
  float* S     = (float*)(ws + 16552960);       // 4,194,304
  float* cqwT  = (float*)(ws + 20747264);       // 114,688
  float* cquwT = (float*)(ws + 20861952);       // 32,768
  float* wwT   = (float*)(ws + 20894720);       // 20,736
  float* lwT   = (float*)(ws + 20915456);       // 12,288  (end 20,927,744)

  hipMemsetAsync(cnt, 0, 31 * sizeof(int), stream);
  setup_kernel<<<1005, 256, 0, stream>>>(x, cnt, Wih, Whh, wl, bihp, bhhp,
      cqw, cquw, ww, l1w, l2w, Wcb, wlb, bias, cqwT, cquwT, wwT, lwT);
  means_kernel<<<7936, 256, 0, stream>>>(x, we, cnt, Mbf);
  lstm_kernel<<<256, 256, 0, stream>>>(Wcb, wlb, bias, Mbf, h0, c0, bl, S);
  final_kernel<<<512, 256, 0, stream>>>(x, Mbf, S,
      c1w, c1b, c2w, c2b, l1b, l2b,
      wwT, wb, cqwT, cqb, cquwT, cqub, lwT, dww, dwb, (float*)d_out);
}

// Round 4
// 342.042 us; speedup vs baseline: 2.4546x; 1.0366x over previous
//
#include <hip/hip_runtime.h>
#include <math.h>

#define BN 4096
typedef unsigned short u16;
typedef unsigned int   u32;
typedef short bfx8 __attribute__((ext_vector_type(8)));
typedef float fx4  __attribute__((ext_vector_type(4)));

// ---- chunk tables: (base row in x, rows used) for the 31 masked means ----
__device__ const int c_base[31] = {
  276,
  211, 224, 237, 250, 263,
  662, 672, 682, 692, 702,
  612, 622, 632, 642, 652,
  397, 410, 423, 436, 449,
  512, 522, 532, 542, 552,
  862, 872, 882, 892, 902
};
__device__ const int c_rows[31] = {
  10,
  10,10,10,10,10,
  5,5,5,5,5,
  5,5,5,5,5,
  10,10,10,10,10,
  5,5,5,5,5,
  5,5,5,5,5
};

__device__ __forceinline__ u16 f2bf(float f){
  u32 u = __float_as_uint(f);
  return (u16)((u + 0x7FFFu + ((u >> 16) & 1u)) >> 16);   // RNE
}
__device__ __forceinline__ float bf2f(u16 h){ return __uint_as_float(((u32)h) << 16); }
__device__ __forceinline__ float4 ld4(const float* p){ return *(const float4*)p; }
__device__ __forceinline__ float frcp(float x){ return __builtin_amdgcn_rcpf(x); }
// sigmoid/tanh via v_exp_f32 + v_rcp_f32 (~1e-6 rel err, << bf16 rounding)
__device__ __forceinline__ float sigf(float v){ return frcp(1.f + __expf(-v)); }
__device__ __forceinline__ float tanhf_(float v){ return 1.f - 2.f*frcp(1.f + __expf(2.f*v)); }

// ---- Kernel 1: sign-count partials. Block (c,part) writes its own slot:
// no atomics, no zero-init needed (each slot written exactly once). ----
extern "C" __global__ __launch_bounds__(256)
void count_kernel(const float* __restrict__ x, int* __restrict__ cnt8){
  __shared__ int red[256];
  const int c = blockIdx.x >> 3, part = blockIdx.x & 7;
  const int base = c_base[c], rows = c_rows[c];
  const int n_per = rows * 512;
  const int start = part * n_per;
  int s = 0;
  for (int i = start + threadIdx.x; i < start + n_per; i += 256){
    float v = x[(size_t)(base + (i >> 12)) * BN + (i & 4095)];
    s += (v > 0.f) ? 1 : ((v < 0.f) ? -1 : 0);
  }
  red[threadIdx.x] = s; __syncthreads();
  for (int off = 128; off > 0; off >>= 1){
    if (threadIdx.x < off) red[threadIdx.x] += red[threadIdx.x + off];
    __syncthreads();
  }
  if (threadIdx.x == 0) cnt8[blockIdx.x] = red[0];
}

// ---- Kernel 2: means (blocks 0..3967, 8 batch/wave) + weight prep (rest) ----
template<int ROWS>
__device__ __forceinline__ void means_body8(const float* __restrict__ x,
                                            const float* __restrict__ we,
                                            float L, int base, int b0, int lane,
                                            float* m){
  float a[8];
  #pragma unroll
  for (int j = 0; j < 8; ++j) a[j] = 0.f;
  #pragma unroll
  for (int r = 0; r < ROWS; ++r){
    float4 i0 = ld4(x + (size_t)(base + r) * BN + b0);
    float4 i1 = ld4(x + (size_t)(base + r) * BN + b0 + 4);
    float wr = ((float)r < L) ? 1.f : 0.f;
    a[0] += wr * we[(size_t)(int)i0.x * 64 + lane];
    a[1] += wr * we[(size_t)(int)i0.y * 64 + lane];
    a[2] += wr * we[(size_t)(int)i0.z * 64 + lane];
    a[3] += wr * we[(size_t)(int)i0.w * 64 + lane];
    a[4] += wr * we[(size_t)(int)i1.x * 64 + lane];
    a[5] += wr * we[(size_t)(int)i1.y * 64 + lane];
    a[6] += wr * we[(size_t)(int)i1.z * 64 + lane];
    a[7] += wr * we[(size_t)(int)i1.w * 64 + lane];
  }
  float rL = 1.f / L;
  #pragma unroll
  for (int j = 0; j < 8; ++j) m[j] = a[j] * rL;
}

extern "C" __global__ __launch_bounds__(256)
void meansprep_kernel(const float* __restrict__ x, const float* __restrict__ we,
                      const int* __restrict__ cnt8, u16* __restrict__ Mbf,
                      const float* __restrict__ Wih, const float* __restrict__ Whh,
                      const float* __restrict__ wl,  const float* __restrict__ bih,
                      const float* __restrict__ bhh,
                      const float* __restrict__ cqw, const float* __restrict__ cquw,
                      const float* __restrict__ ww,  const float* __restrict__ l1w,
                      const float* __restrict__ l2w,
                      u16* __restrict__ Wcb, u16* __restrict__ wlb,
                      float* __restrict__ bias_sum,
                      float* __restrict__ cqwT, float* __restrict__ cquwT,
                      float* __restrict__ wwT,  float* __restrict__ lwT){
  const int blk = blockIdx.x;
  if (blk < 3968){
    const int c = blk >> 7, tile = blk & 127;
    const int w = threadIdx.x >> 6, lane = threadIdx.x & 63;
    const int b0 = tile * 32 + w * 8;
    const int base = c_base[c], rows = c_rows[c];
    int n = 0;
    #pragma unroll
    for (int p = 0; p < 8; ++p) n += cnt8[c*8 + p];
    const float L = fminf(fmaxf((float)n, 1.f), (float)rows);
    float m[8];
    if (rows == 5) means_body8<5>(x, we, L, base, b0, lane, m);
    else          means_body8<10>(x, we, L, base, b0, lane, m);
    #pragma unroll
    for (int j = 0; j < 8; ++j)
      Mbf[((size_t)c * BN + b0 + j) * 64 + lane] = f2bf(m[j]);
    return;
  }
  int idx = (blk - 3968) * 256 + threadIdx.x;
  if (idx < 131072){
    int s = idx >> 15, rem = idx & 32767, n = rem >> 7, k = rem & 127;
    float v = (k < 64) ? Wih[s*16384 + n*64 + k] : Whh[s*16384 + n*64 + (k-64)];
    Wcb[idx] = f2bf(v);
  } else if (idx < 147456){
    int j = idx - 131072;
    wlb[j] = f2bf(wl[j]);
  } else if (idx < 148480){
    int j = idx - 147456;
    bias_sum[j] = bih[j] + bhh[j];
  } else if (idx < 177152){
    int j = idx - 148480;                    // cqwT[448][64]
    int k = j >> 6, m = j & 63;
    cqwT[j] = cqw[m*448 + k];
  } else if (idx < 185344){
    int j = idx - 177152;                    // cquwT[128][64]
    int k = j >> 6, m = j & 63;
    cquwT[j] = cquw[m*128 + k];
  } else if (idx < 190528){
    int j = idx - 185344;                    // wwT[81][64]
    int k = j >> 6, m = j & 63;
    wwT[j] = ww[m*81 + k];
  } else if (idx < 193600){
    int j = idx - 190528;                    // lwT[2][24][64]
    int cs = j >= 1536;
    int r = j - (cs ? 1536 : 0);
    int k = r >> 6, m = r & 63;
    lwT[j] = (cs ? l2w : l1w)[m*24 + k];
  }
}

// ---- Kernel 3: LSTM streams via bf16 MFMA ----
extern "C" __global__ __launch_bounds__(256, 1)
void lstm_kernel(const u16* __restrict__ Wcb, const u16* __restrict__ wlb,
                 const float* __restrict__ bias_sum, const u16* __restrict__ Mbf,
                 const float* __restrict__ h0, const float* __restrict__ c0,
                 const float* __restrict__ bl, float* __restrict__ S){
  __shared__ u16 Xh[64][136];

  const int tid = threadIdx.x, w = tid >> 6, lane = tid & 63;
  const int quad = lane >> 4, l0 = lane & 15;
  const int st = blockIdx.x & 3, tile = blockIdx.x >> 2, b0 = tile * 64;
  const int brow = 16 * w + l0;
  const u16* Wc = Wcb + (size_t)st * 32768;

  fx4 bias4[16];
  #pragma unroll
  for (int mt = 0; mt < 16; ++mt)
    bias4[mt] = *(const fx4*)(bias_sum + st*256 + mt*16 + quad*4);

  float cst[4][4];
  #pragma unroll
  for (int dc = 0; dc < 4; ++dc){
    float4 v = ld4(c0 + ((size_t)st*BN + b0 + brow)*64 + dc*16 + quad*4);
    cst[dc][0]=v.x; cst[dc][1]=v.y; cst[dc][2]=v.z; cst[dc][3]=v.w;
  }
  {
    const float* hp = h0 + ((size_t)st*BN + b0 + brow)*64 + quad*16;
    #pragma unroll
    for (int i = 0; i < 4; ++i){
      float4 v = ld4(hp + i*4);
      u32* dst = (u32*)&Xh[brow][64 + quad*16 + i*4];
      dst[0] = (u32)f2bf(v.x) | ((u32)f2bf(v.y) << 16);
      dst[1] = (u32)f2bf(v.z) | ((u32)f2bf(v.w) << 16);
    }
  }

  for (int t = 0; t < 5; ++t){
    {
      const u16* src = Mbf + ((size_t)(1 + st*5 + t)*BN + b0 + brow)*64 + quad*16;
      *(uint4*)&Xh[brow][quad*16]     = *(const uint4*)src;
      *(uint4*)&Xh[brow][quad*16 + 8] = *(const uint4*)(src + 8);
    }
    __syncthreads();

    fx4 acc[16];
    #pragma unroll
    for (int mt = 0; mt < 16; ++mt) acc[mt] = bias4[mt];
    #pragma unroll
    for (int kc = 0; kc < 4; ++kc){
      bfx8 bfr = *(const bfx8*)&Xh[brow][kc*32 + quad*8];
      #pragma unroll
      for (int mt = 0; mt < 16; ++mt){
        bfx8 afr = *(const bfx8*)(Wc + (size_t)(mt*16 + l0)*128 + kc*32 + quad*8);
        acc[mt] = __builtin_amdgcn_mfma_f32_16x16x32_bf16(afr, bfr, acc[mt], 0, 0, 0);
      }
    }
    #pragma unroll
    for (int dc = 0; dc < 4; ++dc){
      u16 hv[4];
      #pragma unroll
      for (int r = 0; r < 4; ++r){
        float ig = sigf(acc[dc][r]);
        float fg = sigf(acc[4 + dc][r]);
        float gg = tanhf_(acc[8 + dc][r]);
        float og = sigf(acc[12 + dc][r]);
        float cc = fg * cst[dc][r] + ig * gg;
        cst[dc][r] = cc;
        hv[r] = f2bf(og * tanhf_(cc));
      }
      u32* dst = (u32*)&Xh[brow][64 + dc*16 + quad*4];
      dst[0] = (u32)hv[0] | ((u32)hv[1] << 16);
      dst[1] = (u32)hv[2] | ((u32)hv[3] << 16);
    }
    __syncthreads();
  }

  fx4 acc2[4];
  #pragma unroll
  for (int mt = 0; mt < 4; ++mt){ acc2[mt].x=0.f; acc2[mt].y=0.f; acc2[mt].z=0.f; acc2[mt].w=0.f; }
  #pragma unroll
  for (int kc = 0; kc < 2; ++kc){
    bfx8 bfr = *(const bfx8*)&Xh[brow][64 + kc*32 + quad*8];
    #pragma unroll
    for (int mt = 0; mt < 4; ++mt){
      bfx8 afr = *(const bfx8*)(wlb + (size_t)st*4096 + (size_t)(mt*16 + l0)*64 + kc*32 + quad*8);
      acc2[mt] = __builtin_amdgcn_mfma_f32_16x16x32_bf16(afr, bfr, acc2[mt], 0, 0, 0);
    }
  }
  #pragma unroll
  for (int mt = 0; mt < 4; ++mt){
    fx4 blv = *(const fx4*)(bl + st*64 + mt*16 + quad*4);
    fx4 o;
    o.x = tanhf_(acc2[mt].x + blv.x);
    o.y = tanhf_(acc2[mt].y + blv.y);
    o.z = tanhf_(acc2[mt].z + blv.z);
    o.w = tanhf_(acc2[mt].w + blv.w);
    *(fx4*)(S + ((size_t)st*BN + b0 + brow)*64 + mt*16 + quad*4) = o;
  }
}

// ---- Kernel 4: tail. Block = 8 batch, thread = (b = tid&7, mg = tid>>3). ----
extern "C" __global__ __launch_bounds__(256)
void final_kernel(
    const float* __restrict__ x,   const u16* __restrict__ Mbf,
    const float* __restrict__ S,
    const float* __restrict__ c1w, const float* __restrict__ c1b,
    const float* __restrict__ c2w, const float* __restrict__ c2b,
    const float* __restrict__ l1b, const float* __restrict__ l2b,
    const float* __restrict__ wwT, const float* __restrict__ wb,
    const float* __restrict__ cqwT,const float* __restrict__ cqb,
    const float* __restrict__ cquwT,const float* __restrict__ cqub,
    const float* __restrict__ lwT, const float* __restrict__ dww,
    const float* __restrict__ dwb, float* __restrict__ out)
{
  __shared__ float cb[448][9];
  __shared__ float qwin[128][9];
  __shared__ float sm[5][64][9];
  __shared__ float co[48][9];
  __shared__ float cwS[12][130];
  __shared__ float red[32][8];

  const int tid = threadIdx.x;
  const int b   = tid & 7;
  const int mg  = tid >> 3;
  const int b0  = blockIdx.x * 8;

  {
    const int e = tid & 63, rr = tid >> 6;
    #pragma unroll
    for (int i = 0; i < 2; ++i){
      const int bb = rr*2 + i;
      cb[e][bb] = bf2f(Mbf[(size_t)(b0 + bb)*64 + e]);
      #pragma unroll
      for (int s = 0; s < 4; ++s)
        cb[64 + s*64 + e][bb] = S[((size_t)s*BN + b0 + bb)*64 + e];
    }
  }

  {
    float a0 = wb[mg*2], a1 = wb[mg*2+1];
    #pragma unroll 4
    for (int k = 0; k < 81; ++k){
      float xv = x[(size_t)k*BN + b0 + b];
      float2 wv = *(const float2*)(wwT + k*64 + mg*2);
      a0 += wv.x * xv; a1 += wv.y * xv;
    }
    qwin[64 + mg*2][b]     = tanhf_(a0);
    qwin[64 + mg*2 + 1][b] = tanhf_(a1);
  }

  for (int cs = 0; cs < 2; ++cs){
    const float* cw    = cs ? c2w : c1w;
    const float* cbias = cs ? c2b : c1b;
    const float* lb    = cs ? l2b : l1b;

    __syncthreads();
    {
      const int e = tid & 63, rr = tid >> 6;
      #pragma unroll
      for (int t = 0; t < 5; ++t)
        #pragma unroll
        for (int i = 0; i < 2; ++i){
          const int bb = rr*2 + i;
          sm[t][e][bb] = bf2f(Mbf[((size_t)(21 + cs*5 + t)*BN + b0 + bb)*64 + e]);
        }
      for (int r2 = tid; r2 < 1536; r2 += 256){
        const int o = r2 >> 7, j = r2 & 127;
        cwS[o][j] = cw[o*128 + j];
      }
    }
    __syncthreads();

    if (mg < 24){
      const int o = mg >> 1, hb = (mg & 1) * 2;
      float a0 = cbias[o], a1 = cbias[o];
      #pragma unroll 4
      for (int e = 0; e < 64; ++e){
        float w0 = cwS[o][e], w1 = cwS[o][64 + e];
        float s0 = sm[hb][e][b], s1 = sm[hb+1][e][b], s2 = sm[hb+2][e][b];
        a0 += w0*s0 + w1*s1;
        a1 += w0*s1 + w1*s2;
      }
      co[o*4 + hb][b]     = fmaxf(a0, 0.f);
      co[o*4 + hb + 1][b] = fmaxf(a1, 0.f);
    }
    __syncthreads();

    {
      float a0 = lb[mg*2], a1 = lb[mg*2+1];
      #pragma unroll
      for (int k = 0; k < 24; ++k){
        const int p = k >= 12, o = k - (p ? 12 : 0);
        float f = fmaxf(co[o*4 + 2*p][b], co[o*4 + 2*p + 1][b]);
        float2 lv = *(const float2*)(lwT + (cs*24 + k)*64 + mg*2);
        a0 += lv.x * f; a1 += lv.y * f;
      }
      cb[320 + cs*64 + mg*2][b]     = fmaxf(a0, 0.f);
      cb[320 + cs*64 + mg*2 + 1][b] = fmaxf(a1, 0.f);
    }
  }

  __syncthreads();
  {
    float a0 = cqb[mg*2], a1 = cqb[mg*2+1];
    #pragma unroll 8
    for (int k = 0; k < 448; ++k){
      float a = cb[k][b];
      float2 wv = *(const float2*)(cqwT + k*64 + mg*2);
      a0 += wv.x * a; a1 += wv.y * a;
    }
    qwin[mg*2][b]     = tanhf_(a0);
    qwin[mg*2 + 1][b] = tanhf_(a1);
  }
  __syncthreads();
  {
    float a0 = cqub[mg*2], a1 = cqub[mg*2+1];
    #pragma unroll 8
    for (int k = 0; k < 128; ++k){
      float a = qwin[k][b];
      float2 wv = *(const float2*)(cquwT + k*64 + mg*2);
      a0 += wv.x * a; a1 += wv.y * a;
    }
    float2 dv = *(const float2*)(dww + mg*2);
    red[mg][b] = dv.x * tanhf_(a0) + dv.y * tanhf_(a1);
  }
  __syncthreads();
  if (tid < 8){
    float s = dwb[0];
    #pragma unroll 8
    for (int g = 0; g < 32; ++g) s += red[g][tid];
    out[b0 + tid] = s;
  }
}

extern "C" void kernel_launch(void* const* d_in, const int* in_sizes, int n_in,
                              void* d_out, int out_size, void* d_ws, size_t ws_size,
                              hipStream_t stream) {
  const float* x    = (const float*)d_in[0];
  const float* we   = (const float*)d_in[1];
  const float* Wih  = (const float*)d_in[2];
  const float* Whh  = (const float*)d_in[3];
  const float* bihp = (const float*)d_in[4];
  const float* bhhp = (const float*)d_in[5];
  const float* h0   = (const float*)d_in[6];
  const float* c0   = (const float*)d_in[7];
  const float* wl   = (const float*)d_in[8];
  const float* bl   = (const float*)d_in[9];
  const float* c1w  = (const float*)d_in[10];
  const float* c1b  = (const float*)d_in[11];
  const float* l1w  = (const float*)d_in[12];
  const float* l1b  = (const float*)d_in[13];
  const float* c2w  = (const float*)d_in[14];
  const float* c2b  = (const float*)d_in[15];
  const float* l2w  = (const float*)d_in[16];
  const float* l2b  = (const float*)d_in[17];
  const float* ww   = (const float*)d_in[18];
  const float* wb   = (const float*)d_in[19];
  const float* cqw  = (const float*)d_in[20];
  const float* cqb  = (const float*)d_in[21];
  const float* cquw = (const float*)d_in[22];
  const float* cqub = (const float*)d_in[23];
  const float* dww  = (const float*)d_in[24];
  const float* dwb  = (const float*)d_in[25];

  char* ws = (char*)d_ws;
  int*   cnt8  = (int*)ws;                      // 31*8 ints = 992 B (pad 1024)
  u16*   Mbf   = (u16*)(ws + 1024);             // 16,252,928
  u16*   Wcb   = (u16*)(ws + 16253952);         // 262,144
  u16*   wlb   = (u16*)(ws + 16516096);         // 32,768
  float* bias  = (float*)(ws + 16548864);       // 4,096
  float* S     = (float*)(ws + 16552960);       // 4,194,304
  float* cqwT  = (float*)(ws + 20747264);       // 114,688
  float* cquwT = (float*)(ws + 20861952);       // 32,768
  float* wwT   = (float*)(ws + 20894720);       // 20,736
  float* lwT   = (float*)(ws + 20915456);       // 12,288

  count_kernel<<<248, 256, 0, stream>>>(x, cnt8);
  meansprep_kernel<<<4725, 256, 0, stream>>>(x, we, cnt8, Mbf,
      Wih, Whh, wl, bihp, bhhp, cqw, cquw, ww, l1w, l2w,
      Wcb, wlb, bias, cqwT, cquwT, wwT, lwT);
  lstm_kernel<<<256, 256, 0, stream>>>(Wcb, wlb, bias, Mbf, h0, c0, bl, S);
  final_kernel<<<512, 256, 0, stream>>>(x, Mbf, S,
      c1w, c1b, c2w, c2b, l1b, l2b,
      wwT, wb, cqwT, cqb, cquwT, cqub, lwT, dww, dwb, (float*)d_out);
}